// Round 13
// baseline (2591.476 us; speedup 1.0000x reference)
//
#include <hip/hip_runtime.h>
#include <cstdint>

constexpr int Bn = 128, Tn = 1024, Dn = 64, Hn = 256, On = 128;

typedef __fp16 h2 __attribute__((ext_vector_type(2)));
typedef unsigned short u16;

__device__ __forceinline__ float fast_tanh(float x) {
  float e = __expf(2.0f * x);
  return 1.0f - 2.0f / (e + 1.0f);
}

__device__ __forceinline__ float fdot2(h2 a, h2 b, float c) {
#if __has_builtin(__builtin_amdgcn_fdot2)
  return __builtin_amdgcn_fdot2(a, b, c, false);
#else
  return fmaf((float)a.y, (float)b.y, fmaf((float)a.x, (float)b.x, c));
#endif
}

__device__ __forceinline__ h2 pk2(float a, float b) {
  h2 r; r.x = (__fp16)a; r.y = (__fp16)b; return r;
}
__device__ __forceinline__ h2 bits2h(unsigned u) { return __builtin_bit_cast(h2, u); }
__device__ __forceinline__ unsigned h2bits(h2 v) { return __builtin_bit_cast(unsigned, v); }
__device__ __forceinline__ u16 f2hb(float f) {
  __fp16 h = (__fp16)f; return __builtin_bit_cast(u16, h);
}
__device__ __forceinline__ float hb2f(u16 b) {
  return (float)__builtin_bit_cast(__fp16, b);
}
__device__ __forceinline__ void pin16(h2& w) { asm volatile("" : "+v"(w)); }

template <int CTRL>
__device__ __forceinline__ float dpp_add(float v) {
  int s = __builtin_amdgcn_update_dpp(0, __float_as_int(v), CTRL, 0xF, 0xF, true);
  return v + __int_as_float(s);
}
__device__ __forceinline__ float row16_sum(float v) {
  v = dpp_add<0xB1>(v);   // quad_perm xor1
  v = dpp_add<0x4E>(v);   // quad_perm xor2
  v = dpp_add<0x141>(v);  // ROW_HALF_MIRROR == xor4
  v = dpp_add<0x140>(v);  // ROW_MIRROR == xor8
  return v;
}
__device__ __forceinline__ float sel8(int ks, float s0, float s1, float s2,
                                      float s3, float s4, float s5, float s6,
                                      float s7) {
  float u0 = (ks & 1) ? s1 : s0;
  float u1 = (ks & 1) ? s3 : s2;
  float u2 = (ks & 1) ? s5 : s4;
  float u3 = (ks & 1) ? s7 : s6;
  float v0 = (ks & 2) ? u1 : u0;
  float v1 = (ks & 2) ? u3 : u2;
  return (ks & 4) ? v1 : v0;
}

// K=256 slice dot: 8 k-pairs of this thread's slice vs 8 columns.
__device__ __forceinline__ void dot256(const h2 (&w)[8][8], const u16* hbase,
                                       float (&a)[8]) {
  const uint2* hq = (const uint2*)hbase;
  uint2 q0 = hq[0], q1 = hq[1], q2 = hq[2], q3 = hq[3];
  const unsigned d[8] = {q0.x, q0.y, q1.x, q1.y, q2.x, q2.y, q3.x, q3.y};
  #pragma unroll
  for (int p = 0; p < 8; ++p) {
    h2 hp = bits2h(d[p]);
    #pragma unroll
    for (int c = 0; c < 8; ++c) a[c] = fdot2(hp, w[p][c], a[c]);
  }
}
__device__ __forceinline__ float reduce_sel(float (&a)[8], int ks) {
  float s0 = row16_sum(a[0]), s1 = row16_sum(a[1]);
  float s2 = row16_sum(a[2]), s3 = row16_sum(a[3]);
  float s4 = row16_sum(a[4]), s5 = row16_sum(a[5]);
  float s6 = row16_sum(a[6]), s7 = row16_sum(a[7]);
  return sel8(ks, s0, s1, s2, s3, s4, s5, s6, s7);
}

// ---------------------------------------------------------------------------
// Stage 1, TWO BATCHES PER WG (weights are batch-invariant -> zero extra
// weight registers; barrier/latency tail amortized over 2 recurrences; only
// 128 WGs total so every WG gets its own CU — no A/B CU sharing).
//   WGs [0,64):   role A — scan1 for batches {2i, 2i+1}; flag per 32-step blk
//   WGs [64,128): role B — u2 = h1@Wx2+b2 in place (f16) for the same pair
// ---------------------------------------------------------------------------
__global__ __launch_bounds__(512, 1) void stage1_kernel(
    const float* __restrict__ x,    // [B,T,64] f32
    const float* __restrict__ Wx1,  // [64,256] f32
    const float* __restrict__ Wh1,  // [256,256] f32
    const float* __restrict__ b1,   // [256]
    const float* __restrict__ Wx2,  // [256,256] f32
    const float* __restrict__ b2,   // [256]
    u16* __restrict__ h1b16,        // [B,T,256] f16: h1 then (in-place) u2
    int* __restrict__ flags) {      // [64] per-pair block counter
  __shared__ alignas(16) u16 smemU[10240];  // 20 KB (union of roles)
  const int tid = threadIdx.x;
  const int ks = tid & 15;
  const int cg = tid >> 4;
  const int col0 = 8 * cg;
  const int jcol = col0 + (ks & 7);
  const bool writer = (ks < 8);

  if (blockIdx.x < 64) {
    // ================= ROLE A: scan1 producer, batches b0/b1 ==============
    const int pr = blockIdx.x;
    const int b0 = 2 * pr, b1i = 2 * pr + 1;
    const float* xb0 = x + (size_t)b0 * Tn * Dn;
    const float* xb1 = x + (size_t)b1i * Tn * Dn;
    u16* hb0 = h1b16 + (size_t)b0 * Tn * Hn;
    u16* hb1 = h1b16 + (size_t)b1i * Tn * Hn;
    u16* hcH0 = smemU;           // 2 x 320 halfs
    u16* hcH1 = smemU + 640;     // 2 x 320 halfs
    u16* xsH0 = smemU + 1280;    // 2 x 2048 halfs
    u16* xsH1 = smemU + 5376;    // 2 x 2048 halfs

    h2 wh[8][8];
    #pragma unroll
    for (int p = 0; p < 8; ++p) {
      const float* r0 = Wh1 + (size_t)(16 * ks + 2 * p) * Hn + col0;
      float4 a0 = *(const float4*)r0, a1 = *(const float4*)(r0 + 4);
      float4 c0 = *(const float4*)(r0 + Hn), c1 = *(const float4*)(r0 + Hn + 4);
      wh[p][0] = pk2(a0.x, c0.x); wh[p][1] = pk2(a0.y, c0.y);
      wh[p][2] = pk2(a0.z, c0.z); wh[p][3] = pk2(a0.w, c0.w);
      wh[p][4] = pk2(a1.x, c1.x); wh[p][5] = pk2(a1.y, c1.y);
      wh[p][6] = pk2(a1.z, c1.z); wh[p][7] = pk2(a1.w, c1.w);
    }
    h2 wx[2][8];
    #pragma unroll
    for (int p = 0; p < 2; ++p) {
      const float* r0 = Wx1 + (size_t)(4 * ks + 2 * p) * Hn + col0;
      float4 a0 = *(const float4*)r0, a1 = *(const float4*)(r0 + 4);
      float4 c0 = *(const float4*)(r0 + Hn), c1 = *(const float4*)(r0 + Hn + 4);
      wx[p][0] = pk2(a0.x, c0.x); wx[p][1] = pk2(a0.y, c0.y);
      wx[p][2] = pk2(a0.z, c0.z); wx[p][3] = pk2(a0.w, c0.w);
      wx[p][4] = pk2(a1.x, c1.x); wx[p][5] = pk2(a1.y, c1.y);
      wx[p][6] = pk2(a1.z, c1.z); wx[p][7] = pk2(a1.w, c1.w);
    }
    #pragma unroll
    for (int p = 0; p < 8; ++p)
      #pragma unroll
      for (int c = 0; c < 8; ++c) pin16(wh[p][c]);
    #pragma unroll
    for (int p = 0; p < 2; ++p)
      #pragma unroll
      for (int c = 0; c < 8; ++c) pin16(wx[p][c]);

    const float bj = b1[jcol];
    const int woffH = 20 * (jcol >> 4) + (jcol & 15);

    for (int i = tid; i < 1280; i += 512) smemU[i] = 0;  // zero hc0/hc1
    {
      float4 xv0 = *(const float4*)(xb0 + 4 * tid);
      ((uint2*)xsH0)[tid] = make_uint2(h2bits(pk2(xv0.x, xv0.y)), h2bits(pk2(xv0.z, xv0.w)));
      float4 xv1 = *(const float4*)(xb1 + 4 * tid);
      ((uint2*)xsH1)[tid] = make_uint2(h2bits(pk2(xv1.x, xv1.y)), h2bits(pk2(xv1.z, xv1.w)));
    }
    __syncthreads();

    u16 hreg0[8], hreg1[8];
    float4 xr0 = make_float4(0.f, 0.f, 0.f, 0.f), xr1 = xr0;
    for (int t8 = 0; t8 < 128; ++t8) {
      const int xcur = (t8 >> 2) & 1;
      #pragma unroll
      for (int s = 0; s < 8; ++s) {
        const int t = t8 * 8 + s;
        const int cu = s & 1, nx = cu ^ 1;
        if (s == 0 && (t8 & 3) == 0 && t8 < 124) {
          xr0 = *(const float4*)(xb0 + (size_t)((t8 >> 2) + 1) * 2048 + 4 * tid);
          xr1 = *(const float4*)(xb1 + (size_t)((t8 >> 2) + 1) * 2048 + 4 * tid);
        }
        const int xoff = ((t & 31) << 6) + 4 * ks;
        // ---- batch 0 ----
        {
          float a[8] = {0.f, 0.f, 0.f, 0.f, 0.f, 0.f, 0.f, 0.f};
          dot256(wh, hcH0 + cu * 320 + 20 * ks, a);
          uint2 xq = *(const uint2*)(xsH0 + xcur * 2048 + xoff);
          h2 xp0 = bits2h(xq.x), xp1 = bits2h(xq.y);
          #pragma unroll
          for (int c = 0; c < 8; ++c) {
            a[c] = fdot2(xp0, wx[0][c], a[c]);
            a[c] = fdot2(xp1, wx[1][c], a[c]);
          }
          float h = fast_tanh(reduce_sel(a, ks) + bj);
          u16 hbits = f2hb(h);
          if (writer) hcH0[nx * 320 + woffH] = hbits;
          hreg0[s] = hbits;
        }
        // ---- batch 1 ----
        {
          float a[8] = {0.f, 0.f, 0.f, 0.f, 0.f, 0.f, 0.f, 0.f};
          dot256(wh, hcH1 + cu * 320 + 20 * ks, a);
          uint2 xq = *(const uint2*)(xsH1 + xcur * 2048 + xoff);
          h2 xp0 = bits2h(xq.x), xp1 = bits2h(xq.y);
          #pragma unroll
          for (int c = 0; c < 8; ++c) {
            a[c] = fdot2(xp0, wx[0][c], a[c]);
            a[c] = fdot2(xp1, wx[1][c], a[c]);
          }
          float h = fast_tanh(reduce_sel(a, ks) + bj);
          u16 hbits = f2hb(h);
          if (writer) hcH1[nx * 320 + woffH] = hbits;
          hreg1[s] = hbits;
        }
        if (s == 7) {
          if (writer) {
            u16* d0 = hb0 + (size_t)(t - 7) * Hn + jcol;
            u16* d1 = hb1 + (size_t)(t - 7) * Hn + jcol;
            #pragma unroll
            for (int i = 0; i < 8; ++i) { d0[i * Hn] = hreg0[i]; d1[i * Hn] = hreg1[i]; }
          }
          if ((t8 & 3) == 3 && t8 < 127) {
            ((uint2*)(xsH0 + (xcur ^ 1) * 2048))[tid] =
                make_uint2(h2bits(pk2(xr0.x, xr0.y)), h2bits(pk2(xr0.z, xr0.w)));
            ((uint2*)(xsH1 + (xcur ^ 1) * 2048))[tid] =
                make_uint2(h2bits(pk2(xr1.x, xr1.y)), h2bits(pk2(xr1.z, xr1.w)));
          }
        }
        __syncthreads();  // vmcnt(0) drained -> safe to release
        if (s == 7 && (t8 & 3) == 3 && tid == 0)
          __hip_atomic_store(flags + pr, (t8 >> 2) + 1, __ATOMIC_RELEASE,
                             __HIP_MEMORY_SCOPE_AGENT);
      }
    }
  } else {
    // ================= ROLE B: u2 for pair (f16 in place) =================
    const int pr = blockIdx.x - 64;
    u16* hsH = smemU;  // [32][320] halfs = 20 KB, reused per batch

    h2 w2[8][8];
    #pragma unroll
    for (int p = 0; p < 8; ++p) {
      const float* r0 = Wx2 + (size_t)(16 * ks + 2 * p) * Hn + col0;
      float4 a0 = *(const float4*)r0, a1 = *(const float4*)(r0 + 4);
      float4 c0 = *(const float4*)(r0 + Hn), c1 = *(const float4*)(r0 + Hn + 4);
      w2[p][0] = pk2(a0.x, c0.x); w2[p][1] = pk2(a0.y, c0.y);
      w2[p][2] = pk2(a0.z, c0.z); w2[p][3] = pk2(a0.w, c0.w);
      w2[p][4] = pk2(a1.x, c1.x); w2[p][5] = pk2(a1.y, c1.y);
      w2[p][6] = pk2(a1.z, c1.z); w2[p][7] = pk2(a1.w, c1.w);
    }
    #pragma unroll
    for (int p = 0; p < 8; ++p)
      #pragma unroll
      for (int c = 0; c < 8; ++c) pin16(w2[p][c]);

    const float b2j = b2[jcol];
    const int lr = tid >> 4;
    const int lc = tid & 15;
    u16* ldst = hsH + lr * 320 + 20 * lc;

    u16 ureg[8];
    for (int blk = 0; blk < 32; ++blk) {
      if (tid == 0) {
        while (__hip_atomic_load(flags + pr, __ATOMIC_ACQUIRE,
                                 __HIP_MEMORY_SCOPE_AGENT) < blk + 1)
          __builtin_amdgcn_s_sleep(8);
      }
      __syncthreads();
      #pragma unroll 1
      for (int bi = 0; bi < 2; ++bi) {
        u16* ub = h1b16 + (size_t)(2 * pr + bi) * Tn * Hn;
        {
          const uint4* src = (const uint4*)(ub + (size_t)(blk * 32 + lr) * Hn + 16 * lc);
          uint4 v0 = src[0], v1 = src[1];
          ((uint2*)ldst)[0] = make_uint2(v0.x, v0.y);
          ((uint2*)ldst)[1] = make_uint2(v0.z, v0.w);
          ((uint2*)ldst)[2] = make_uint2(v1.x, v1.y);
          ((uint2*)ldst)[3] = make_uint2(v1.z, v1.w);
        }
        __syncthreads();
        for (int s = 0; s < 32; ++s) {
          float a[8] = {0.f, 0.f, 0.f, 0.f, 0.f, 0.f, 0.f, 0.f};
          dot256(w2, hsH + s * 320 + 20 * ks, a);
          ureg[s & 7] = f2hb(reduce_sel(a, ks) + b2j);
          if ((s & 7) == 7 && writer) {
            u16* dst = ub + (size_t)(blk * 32 + s - 7) * Hn + jcol;
            #pragma unroll
            for (int i = 0; i < 8; ++i) dst[i * Hn] = ureg[i];
          }
        }
        __syncthreads();  // drain u2 stores + protect hsH reuse
      }
    }
  }
}

// ---------------------------------------------------------------------------
// Scan 2, two batches per WG (64 WGs): h2_t = tanh(u2_t + h2_{t-1}@Wh2).
// ---------------------------------------------------------------------------
__global__ __launch_bounds__(512, 1) void scan2_kernel(
    const u16* __restrict__ U,      // [B,T,256] f16
    const float* __restrict__ Wh2,  // [256,256] f32
    float* __restrict__ hfinal) {   // [B,256] f32
  __shared__ alignas(16) u16 hcU[1280];  // 2 batches x 2 x 320 halfs
  const int tid = threadIdx.x;
  const int ks = tid & 15;
  const int cg = tid >> 4;
  const int col0 = 8 * cg;
  const int pr = blockIdx.x;
  const u16* Ub0 = U + (size_t)(2 * pr) * Tn * Hn;
  const u16* Ub1 = U + (size_t)(2 * pr + 1) * Tn * Hn;
  u16* hc0 = hcU;        // [2][320]
  u16* hc1 = hcU + 640;  // [2][320]

  h2 wh[8][8];
  #pragma unroll
  for (int p = 0; p < 8; ++p) {
    const float* r0 = Wh2 + (size_t)(16 * ks + 2 * p) * Hn + col0;
    float4 a0 = *(const float4*)r0, a1 = *(const float4*)(r0 + 4);
    float4 c0 = *(const float4*)(r0 + Hn), c1 = *(const float4*)(r0 + Hn + 4);
    wh[p][0] = pk2(a0.x, c0.x); wh[p][1] = pk2(a0.y, c0.y);
    wh[p][2] = pk2(a0.z, c0.z); wh[p][3] = pk2(a0.w, c0.w);
    wh[p][4] = pk2(a1.x, c1.x); wh[p][5] = pk2(a1.y, c1.y);
    wh[p][6] = pk2(a1.z, c1.z); wh[p][7] = pk2(a1.w, c1.w);
  }
  #pragma unroll
  for (int p = 0; p < 8; ++p)
    #pragma unroll
    for (int c = 0; c < 8; ++c) pin16(wh[p][c]);

  const int jcol = col0 + (ks & 7);
  const bool writer = (ks < 8);
  const int woffH = 20 * (jcol >> 4) + (jcol & 15);

  for (int i = tid; i < 1280; i += 512) hcU[i] = 0;
  __syncthreads();

  float uc0[8], un0[8], uc1[8], un1[8];
  if (writer) {
    #pragma unroll
    for (int i = 0; i < 8; ++i) {
      uc0[i] = hb2f(Ub0[(size_t)i * Hn + jcol]);
      uc1[i] = hb2f(Ub1[(size_t)i * Hn + jcol]);
    }
  }

  for (int t8 = 0; t8 < 128; ++t8) {
    #pragma unroll
    for (int s = 0; s < 8; ++s) {
      const int cu = s & 1, nx = cu ^ 1;
      if (s == 0 && writer && t8 < 127) {
        #pragma unroll
        for (int i = 0; i < 8; ++i) {
          un0[i] = hb2f(Ub0[(size_t)(t8 * 8 + 8 + i) * Hn + jcol]);
          un1[i] = hb2f(Ub1[(size_t)(t8 * 8 + 8 + i) * Hn + jcol]);
        }
      }
      {
        float a[8] = {0.f, 0.f, 0.f, 0.f, 0.f, 0.f, 0.f, 0.f};
        dot256(wh, hc0 + cu * 320 + 20 * ks, a);
        float h = fast_tanh(reduce_sel(a, ks) + uc0[s]);
        if (writer) hc0[nx * 320 + woffH] = f2hb(h);
      }
      {
        float a[8] = {0.f, 0.f, 0.f, 0.f, 0.f, 0.f, 0.f, 0.f};
        dot256(wh, hc1 + cu * 320 + 20 * ks, a);
        float h = fast_tanh(reduce_sel(a, ks) + uc1[s]);
        if (writer) hc1[nx * 320 + woffH] = f2hb(h);
      }
      if (s == 7 && writer) {
        #pragma unroll
        for (int i = 0; i < 8; ++i) { uc0[i] = un0[i]; uc1[i] = un1[i]; }
      }
      __syncthreads();
    }
  }
  if (tid < Hn) {
    const int off = (tid >> 4) * 20 + (tid & 15);
    hfinal[(size_t)(2 * pr) * Hn + tid] = hb2f(hc0[off]);
    hfinal[(size_t)(2 * pr + 1) * Hn + tid] = hb2f(hc1[off]);
  }
}

// ---------------------------------------------------------------------------
// Head: out = softmax(h2_T @ Wd + bd). f32, unchanged.
// ---------------------------------------------------------------------------
__global__ __launch_bounds__(128) void head_kernel(
    const float* __restrict__ hfinal, const float* __restrict__ Wd,
    const float* __restrict__ bd, float* __restrict__ out) {
  __shared__ float hrow[Hn];
  __shared__ float red[On];
  const int o = threadIdx.x;
  const int b = blockIdx.x;
  hrow[o] = hfinal[(size_t)b * Hn + o];
  hrow[o + 128] = hfinal[(size_t)b * Hn + 128 + o];
  __syncthreads();
  float acc = bd[o];
  #pragma unroll 8
  for (int k = 0; k < Hn; ++k) acc = fmaf(hrow[k], Wd[(size_t)k * On + o], acc);
  red[o] = acc;
  __syncthreads();
  #pragma unroll
  for (int s = 64; s > 0; s >>= 1) {
    if (o < s) red[o] = fmaxf(red[o], red[o + s]);
    __syncthreads();
  }
  const float mx = red[0];
  __syncthreads();
  const float e = __expf(acc - mx);
  red[o] = e;
  __syncthreads();
  #pragma unroll
  for (int s = 64; s > 0; s >>= 1) {
    if (o < s) red[o] += red[o + s];
    __syncthreads();
  }
  out[(size_t)b * On + o] = e / red[0];
}

// ---------------------------------------------------------------------------
extern "C" void kernel_launch(void* const* d_in, const int* in_sizes, int n_in,
                              void* d_out, int out_size, void* d_ws, size_t ws_size,
                              hipStream_t stream) {
  const float* x   = (const float*)d_in[0];
  const float* Wx1 = (const float*)d_in[1];
  const float* Wh1 = (const float*)d_in[2];
  const float* b1  = (const float*)d_in[3];
  const float* Wx2 = (const float*)d_in[4];
  const float* Wh2 = (const float*)d_in[5];
  const float* b2  = (const float*)d_in[6];
  const float* Wd  = (const float*)d_in[7];
  const float* bd  = (const float*)d_in[8];
  float* out = (float*)d_out;

  u16* h1b16 = (u16*)d_ws;                                  // [B,T,256] f16
  float* hfinal = (float*)(h1b16 + (size_t)Bn * Tn * Hn);   // [B,256] f32
  int* flags = (int*)(hfinal + (size_t)Bn * Hn);            // [64]

  hipMemsetAsync(flags, 0, 64 * sizeof(int), stream);
  stage1_kernel<<<128, 512, 0, stream>>>(x, Wx1, Wh1, b1, Wx2, b2, h1b16, flags);
  scan2_kernel<<<64, 512, 0, stream>>>(h1b16, Wh2, hfinal);
  head_kernel<<<Bn, 128, 0, stream>>>(hfinal, Wd, bd, out);
}